// Round 14
// baseline (931.475 us; speedup 1.0000x reference)
//
#include <hip/hip_runtime.h>
#include <hip/hip_cooperative_groups.h>

namespace cg = cooperative_groups;

#define NEG 0.2f

typedef short s16x8 __attribute__((ext_vector_type(8)));
typedef float f32x4 __attribute__((ext_vector_type(4)));

__device__ __forceinline__ float lrelu(float x) { return x >= 0.f ? x : NEG * x; }
__device__ __forceinline__ float elu1(float x) { return x > 0.f ? x : __expf(x) - 1.f; }

__device__ __forceinline__ unsigned bf16rn(float f) {
    unsigned u = __float_as_uint(f);
    u += 0x7fffu + ((u >> 16) & 1u);
    return u >> 16;
}
__device__ __forceinline__ float bf16tof(ushort h) {
    return __uint_as_float(((unsigned)h) << 16);
}
__device__ __forceinline__ float bf16lo(unsigned u) { return __uint_as_float(u << 16); }
__device__ __forceinline__ float bf16hi(unsigned u) { return __uint_as_float(u & 0xffff0000u); }

__device__ __forceinline__ int waveIncScanI(int v, int lane) {
#pragma unroll
    for (int off = 1; off < 64; off <<= 1) {
        int u = __shfl_up(v, off);
        if (lane >= off) v += u;
    }
    return v;
}

// ----------------- cooperative build: wpack + deg-zero + hist + scan + fill in ONE dispatch.
// XCD-partitioned hist/fill (blockIdx%8 = dst range -> single-XCD lines, L2-local atomics).
// Phase ordering via cg::grid_group::sync() (+ explicit device fence for cross-XCD writeback).
__global__ void coopbuild_kernel(const int* __restrict__ src, const int* __restrict__ dst,
                                 int e, int n,
                                 const float* __restrict__ w_in, const float* __restrict__ w0,
                                 const float* __restrict__ w1, const float* __restrict__ w2,
                                 const float* __restrict__ b_in,
                                 ushort* __restrict__ whi, ushort* __restrict__ wlo,
                                 float* __restrict__ beff,
                                 int* __restrict__ deg, int* __restrict__ rowp,
                                 int* __restrict__ col, int* __restrict__ bsums) {
    cg::grid_group grid = cg::this_grid();
    int b = blockIdx.x, t = threadIdx.x;
    int gid = b * 256 + t;
    int gstride = gridDim.x * 256;
    int nb = (n + 2047) / 2048;

    // ---- P0: zero deg + pack weights (layer0 = w_in@w0 folded; layers 1,2 direct) ----
    for (int i = gid; i < n; i += gstride) deg[i] = 0;
    if (gid < 3 * 16384) {
        int layer = gid >> 14, ee = gid & 16383;
        int k = ee >> 7, c = ee & 127;
        float wv;
        if (layer == 0) {
            float s = 0.f;
            for (int m = 0; m < 128; ++m) s += w_in[k * 128 + m] * w0[m * 128 + c];
            wv = s;
        } else {
            const float* W = (layer == 1) ? w1 : w2;
            wv = W[ee];
        }
        ushort hi = (ushort)bf16rn(wv);
        ushort lo = (ushort)bf16rn(wv - bf16tof(hi));
        int kt = k >> 5, kk = k & 31, j = kk & 7;
        int ln = ((kk >> 3) << 4) | (c & 15);
        int ntg = c >> 4;
        int pos = (layer << 14) + (((kt << 3) + ntg) * 64 + ln) * 8 + j;
        whi[pos] = hi;
        wlo[pos] = lo;
        if (gid < 128) {
            float s = 0.f;
            for (int m = 0; m < 128; ++m) s += b_in[m] * w0[m * 128 + gid];
            beff[gid] = s;
        }
    }
    __threadfence();
    grid.sync();

    // ---- P1: histogram (XCD-partitioned) ----
    {
        int p = b & 7, s = b >> 3;
        int nslices = gridDim.x >> 3;
        int rng = (n + 7) >> 3;
        int lo = p * rng, hi = min(n, lo + rng);
        int chunk = (e + nslices - 1) / nslices;
        int i0 = s * chunk, i1 = min(e, i0 + chunk);
        for (int i = i0 + t; i < i1; i += 256) {
            int d = dst[i];
            if (d >= lo && d < hi) atomicAdd(&deg[d], 1);
        }
    }
    __threadfence();
    grid.sync();

    // ---- P2: per-block local exclusive scan -> rowp, block sums -> bsums ----
    if (b < nb) {
        int base = b * 2048 + t * 8;
        int vals[8];
        int sum = 0;
#pragma unroll
        for (int i = 0; i < 8; ++i) {
            int idx = base + i;
            int v = (idx < n) ? deg[idx] : 0;
            vals[i] = sum;
            sum += v;
        }
        int lane = t & 63, w = t >> 6;
        int inc = waveIncScanI(sum, lane);
        __shared__ int wsums[4];
        if (lane == 63) wsums[w] = inc;
        __syncthreads();
        int wpre = 0;
#pragma unroll
        for (int i = 0; i < 3; ++i) wpre += (i < w) ? wsums[i] : 0;
        int exc = wpre + inc - sum;
#pragma unroll
        for (int i = 0; i < 8; ++i) {
            int idx = base + i;
            if (idx < n) rowp[idx] = exc + vals[i];
        }
        if (t == 255) bsums[b] = wpre + inc;
    }
    __threadfence();
    grid.sync();

    // ---- P3: add block prefixes (local lookback over bsums), copy cursor (deg reused) ----
    if (b < nb) {
        __shared__ int spre;
        if (t < 64) {
            int lane = t;
            int v = 0;
            for (int base = lane; base < b; base += 64) v += bsums[base];
#pragma unroll
            for (int off = 32; off > 0; off >>= 1) v += __shfl_xor(v, off);
            if (lane == 0) spre = v;
        }
        __syncthreads();
        int pre = spre;
        int base = b * 2048 + t * 8;
#pragma unroll
        for (int i = 0; i < 8; ++i) {
            int idx = base + i;
            if (idx < n) {
                int v = rowp[idx] + pre;
                rowp[idx] = v;
                deg[idx] = v; // cursor
            } else if (idx == n) {
                rowp[n] = e;
            }
        }
    }
    __threadfence();
    grid.sync();

    // ---- P4: fill col (XCD-partitioned scatter) ----
    {
        int p = b & 7, s = b >> 3;
        int nslices = gridDim.x >> 3;
        int rng = (n + 7) >> 3;
        int lo = p * rng, hi = min(n, lo + rng);
        int chunk = (e + nslices - 1) / nslices;
        int i0 = s * chunk, i1 = min(e, i0 + chunk);
        for (int i = i0 + t; i < i1; i += 256) {
            int d = dst[i];
            if (d >= lo && d < hi) {
                int pos = atomicAdd(&deg[d], 1);
                col[pos] = src[i];
            }
        }
    }
}

// ----------------- MFMA split-bf16 GEMM, double-buffered LDS staging (1 barrier/tile)
// out[n,128](bf16) = A[n,128] @ W[128,128] (+bias); fused attention logits from biased out.
template <bool BIAS, bool AL, bool ABF16>
__global__ __launch_bounds__(512, 2) void gemm_mfma_kernel(
    const void* __restrict__ Av, const ushort* __restrict__ whi, const ushort* __restrict__ wlo,
    const float* __restrict__ bias, ushort* __restrict__ outb, int n, int ntiles,
    const float* __restrict__ asrc, const float* __restrict__ adst,
    float* __restrict__ als, float* __restrict__ ald) {
    __shared__ s16x8 ahi[2][2][4][64]; // [dbuf][mhalf][kt][lane]
    __shared__ s16x8 alo[2][2][4][64];
    int t = threadIdx.x;
    int wid = t >> 6, lane = t & 63;
    int ntp = wid & 3;    // head / 32-col pair
    int mhalf = wid >> 2; // which 16-row half

    const s16x8* wph = (const s16x8*)whi;
    const s16x8* wpl = (const s16x8*)wlo;
    s16x8 wh[4][2], wl[4][2];
#pragma unroll
    for (int kt = 0; kt < 4; ++kt)
#pragma unroll
        for (int j = 0; j < 2; ++j) {
            int ntg = ntp * 2 + j;
            wh[kt][j] = wph[((kt << 3) + ntg) * 64 + lane];
            wl[kt][j] = wpl[((kt << 3) + ntg) * 64 + lane];
        }

    int c0 = ntp * 32 + (lane & 15);
    int c1 = c0 + 16;
    float bv0 = 0.f, bv1 = 0.f;
    if (BIAS) { bv0 = bias[c0]; bv1 = bias[c1]; }
    float as0 = 0.f, as1 = 0.f, ad0 = 0.f, ad1 = 0.f;
    if (AL) {
        as0 = asrc[ntp * 32 + (lane & 15)];
        as1 = asrc[ntp * 32 + 16 + (lane & 15)];
        ad0 = adst[ntp * 32 + (lane & 15)];
        ad1 = adst[ntp * 32 + 16 + (lane & 15)];
    }

    int srow = t >> 4, skoct = t & 15;
    int smh = srow >> 4, skt = skoct >> 2;
    int sln = ((skoct & 3) << 4) | (srow & 15);

    auto stage = [&](int tile, int bi) {
        int gr = tile * 32 + srow;
        if (ABF16) {
            const ushort* Ab = (const ushort*)Av;
            s16x8 hi = {0, 0, 0, 0, 0, 0, 0, 0};
            if (gr < n) hi = *(const s16x8*)(Ab + (size_t)gr * 128 + skoct * 8);
            ahi[bi][smh][skt][sln] = hi;
        } else {
            const float* Af = (const float*)Av;
            float4 v0 = make_float4(0.f, 0.f, 0.f, 0.f), v1 = v0;
            if (gr < n) {
                const float4* rp = (const float4*)(Af + (size_t)gr * 128 + skoct * 8);
                v0 = rp[0];
                v1 = rp[1];
            }
            float f[8] = {v0.x, v0.y, v0.z, v0.w, v1.x, v1.y, v1.z, v1.w};
            s16x8 hi, lo;
#pragma unroll
            for (int j = 0; j < 8; ++j) {
                ushort h = (ushort)bf16rn(f[j]);
                hi[j] = (short)h;
                lo[j] = (short)bf16rn(f[j] - bf16tof(h));
            }
            ahi[bi][smh][skt][sln] = hi;
            alo[bi][smh][skt][sln] = lo;
        }
    };

    int tile = blockIdx.x;
    if (tile < ntiles) stage(tile, 0);
    int cur = 0;
    __syncthreads();

    for (; tile < ntiles; tile += gridDim.x) {
        int nxt = tile + gridDim.x;
        if (nxt < ntiles) stage(nxt, cur ^ 1);

        f32x4 acc0 = {0.f, 0.f, 0.f, 0.f};
        f32x4 acc1 = {0.f, 0.f, 0.f, 0.f};
#pragma unroll
        for (int kt = 0; kt < 4; ++kt) {
            s16x8 ah = ahi[cur][mhalf][kt][lane];
            if (ABF16) {
                acc0 = __builtin_amdgcn_mfma_f32_16x16x32_bf16(ah, wh[kt][0], acc0, 0, 0, 0);
                acc0 = __builtin_amdgcn_mfma_f32_16x16x32_bf16(ah, wl[kt][0], acc0, 0, 0, 0);
                acc1 = __builtin_amdgcn_mfma_f32_16x16x32_bf16(ah, wh[kt][1], acc1, 0, 0, 0);
                acc1 = __builtin_amdgcn_mfma_f32_16x16x32_bf16(ah, wl[kt][1], acc1, 0, 0, 0);
            } else {
                s16x8 al = alo[cur][mhalf][kt][lane];
                acc0 = __builtin_amdgcn_mfma_f32_16x16x32_bf16(ah, wh[kt][0], acc0, 0, 0, 0);
                acc0 = __builtin_amdgcn_mfma_f32_16x16x32_bf16(ah, wl[kt][0], acc0, 0, 0, 0);
                acc0 = __builtin_amdgcn_mfma_f32_16x16x32_bf16(al, wh[kt][0], acc0, 0, 0, 0);
                acc1 = __builtin_amdgcn_mfma_f32_16x16x32_bf16(ah, wh[kt][1], acc1, 0, 0, 0);
                acc1 = __builtin_amdgcn_mfma_f32_16x16x32_bf16(ah, wl[kt][1], acc1, 0, 0, 0);
                acc1 = __builtin_amdgcn_mfma_f32_16x16x32_bf16(al, wh[kt][1], acc1, 0, 0, 0);
            }
        }

        int rbase = tile * 32 + mhalf * 16 + (lane >> 4) * 4;
#pragma unroll
        for (int i = 0; i < 4; ++i) {
            int r = rbase + i;
            float o0 = acc0[i] + bv0;
            float o1 = acc1[i] + bv1;
            if (r < n) {
                outb[(size_t)r * 128 + c0] = (ushort)bf16rn(o0);
                outb[(size_t)r * 128 + c1] = (ushort)bf16rn(o1);
            }
            if (AL) {
                float ps = o0 * as0 + o1 * as1;
                float pd = o0 * ad0 + o1 * ad1;
                ps += __shfl_xor(ps, 1); ps += __shfl_xor(ps, 2);
                ps += __shfl_xor(ps, 4); ps += __shfl_xor(ps, 8);
                pd += __shfl_xor(pd, 1); pd += __shfl_xor(pd, 2);
                pd += __shfl_xor(pd, 4); pd += __shfl_xor(pd, 8);
                if ((lane & 15) == 0 && r < n) {
                    als[r * 4 + ntp] = ps;
                    ald[r * 4 + ntp] = pd;
                }
            }
        }
        __syncthreads();
        cur ^= 1;
    }
}

// ----------------- GAT aggregation: TWO nodes per wave (32 lanes / 4 channels each);
// exp(lrelu(..)) by lane specialization + shfl; bf16 rows; inline self-loop. -----------------
template <bool CONCAT>
__global__ void agg_kernel(const ushort* __restrict__ hp, const float* __restrict__ als,
                           const float* __restrict__ ald_, const int* __restrict__ rowp,
                           const int* __restrict__ col, const float* __restrict__ bias,
                           ushort* __restrict__ outb, float* __restrict__ outf, int n) {
    int lane = threadIdx.x & 63;
    int hl = lane & 31;   // lane within half-wave
    int wid = (blockIdx.x * blockDim.x + threadIdx.x) >> 6;
    int d = wid * 2 + (lane >> 5);
    bool valid = d < n;
    int dc = valid ? d : (n - 1);

    int h = hl >> 3;      // data head (this lane's 4 channels)
    int c4 = hl * 4;      // channel base 0..124
    int hh = hl & 3;      // exp-duty head
    int jl = hl >> 2;     // exp-duty edge slot 0..7
    int bshf = lane & 32; // half base for shuffles

    int start = rowp[dc];
    int end = valid ? rowp[dc + 1] : start;

    float aldv_hh = ald_[dc * 4 + hh];
    float eself = __expf(lrelu(als[dc * 4 + h] + ald_[dc * 4 + h]));

    uint2 sv = *(const uint2*)(hp + (size_t)dc * 128 + c4);
    float a0 = eself * bf16lo(sv.x), a1 = eself * bf16hi(sv.x);
    float a2 = eself * bf16lo(sv.y), a3 = eself * bf16hi(sv.y);
    float esum = eself;

    int iters = (end - start + 7) >> 3;
    int oiters = __shfl_xor(iters, 32);
    int maxit = iters > oiters ? iters : oiters;
    unsigned nclamp = (unsigned)(n - 1);

    for (int it = 0; it < maxit; ++it) {
        int p0 = start + it * 8;
        bool act = p0 < end;
        int pc = act ? p0 : start;
        int4 ca = *(const int4*)(col + pc);
        int4 cb = *(const int4*)(col + pc + 4);
        int v0 = (jl & 4) ? cb.x : ca.x;
        int v1 = (jl & 4) ? cb.y : ca.y;
        int v2 = (jl & 4) ? cb.z : ca.z;
        int v3 = (jl & 4) ? cb.w : ca.w;
        int w0_ = (jl & 2) ? v2 : v0;
        int w1_ = (jl & 2) ? v3 : v1;
        unsigned se = (unsigned)((jl & 1) ? w1_ : w0_);
        se = se > nclamp ? nclamp : se;
        float ee = __expf(lrelu(als[(size_t)se * 4 + hh] + aldv_hh));
        ee = (act && (p0 + jl < end)) ? ee : 0.f;

#define EDGE(JJ, SRC)                                                              \
        {                                                                          \
            float ej = __shfl(ee, bshf | (JJ << 2) | h);                           \
            unsigned sju = (unsigned)(SRC);                                        \
            sju = sju > nclamp ? nclamp : sju;                                     \
            uint2 uv = *(const uint2*)(hp + (size_t)sju * 128 + c4);               \
            a0 += ej * bf16lo(uv.x); a1 += ej * bf16hi(uv.x);                      \
            a2 += ej * bf16lo(uv.y); a3 += ej * bf16hi(uv.y);                      \
            esum += ej;                                                            \
        }
        EDGE(0, ca.x) EDGE(1, ca.y) EDGE(2, ca.z) EDGE(3, ca.w)
        EDGE(4, cb.x) EDGE(5, cb.y) EDGE(6, cb.z) EDGE(7, cb.w)
#undef EDGE
    }

    float inv = 1.f / (esum + 1e-16f);
    a0 *= inv; a1 *= inv; a2 *= inv; a3 *= inv;
    if (CONCAT) {
        if (valid) {
            float o0 = elu1(a0 + bias[c4]);
            float o1 = elu1(a1 + bias[c4 + 1]);
            float o2 = elu1(a2 + bias[c4 + 2]);
            float o3 = elu1(a3 + bias[c4 + 3]);
            uint2 pk;
            pk.x = bf16rn(o0) | (bf16rn(o1) << 16);
            pk.y = bf16rn(o2) | (bf16rn(o3) << 16);
            *(uint2*)(outb + (size_t)d * 128 + c4) = pk;
        }
    } else {
        a0 += __shfl_xor(a0, 8); a0 += __shfl_xor(a0, 16);
        a1 += __shfl_xor(a1, 8); a1 += __shfl_xor(a1, 16);
        a2 += __shfl_xor(a2, 8); a2 += __shfl_xor(a2, 16);
        a3 += __shfl_xor(a3, 8); a3 += __shfl_xor(a3, 16);
        if (valid && hl < 8) {
            int cin = hl * 4;
            float4 o;
            o.x = elu1(a0 * 0.25f + bias[cin]);
            o.y = elu1(a1 * 0.25f + bias[cin + 1]);
            o.z = elu1(a2 * 0.25f + bias[cin + 2]);
            o.w = elu1(a3 * 0.25f + bias[cin + 3]);
            *(float4*)(outf + (size_t)d * 32 + cin) = o;
        }
    }
}

// ----------------- fused mean-pool + final_proj + MLP head, one block per batch row ---------
__global__ void poolmlp_kernel(const float* __restrict__ h2, const int* __restrict__ batch,
                               int n, const float* __restrict__ w_fp,
                               const float* __restrict__ b_fp, const float* __restrict__ w_m1,
                               const float* __restrict__ b_m1, const float* __restrict__ w_m2,
                               const float* __restrict__ b_m2, float* __restrict__ out) {
    int b = blockIdx.x, t = threadIdx.x; // 256 threads
    __shared__ int sb[2];
    if (t == 0) {
        int lo = 0, hi = n;
        while (lo < hi) { int mid = (lo + hi) >> 1; if (batch[mid] < b) lo = mid + 1; else hi = mid; }
        sb[0] = lo;
        int lo2 = lo, hi2 = n;
        while (lo2 < hi2) { int mid = (lo2 + hi2) >> 1; if (batch[mid] < b + 1) lo2 = mid + 1; else hi2 = mid; }
        sb[1] = lo2;
    }
    __syncthreads();
    int lo = sb[0], hi = sb[1];
    int c = t & 31, g = t >> 5; // 8 groups of 32
    float acc = 0.f;
    for (int i = lo + g; i < hi; i += 8) acc += h2[(size_t)i * 32 + c];
    __shared__ float red[8][32];
    __shared__ float sp[32], so[128];
    red[g][c] = acc;
    __syncthreads();
    if (t < 32) {
        float s = 0.f;
#pragma unroll
        for (int g2 = 0; g2 < 8; ++g2) s += red[g2][t];
        float cnt = (float)(hi - lo);
        sp[t] = s / fmaxf(cnt, 1.f);
    }
    __syncthreads();
    if (t < 128) {
        float o = b_fp[t];
#pragma unroll 8
        for (int k = 0; k < 32; ++k) o += sp[k] * w_fp[k * 128 + t];
        so[t] = o;
    }
    __syncthreads();
    if (t < 64) {
        float hm = b_m1[t];
        for (int cc = 0; cc < 128; ++cc) hm += so[cc] * w_m1[cc * 64 + t];
        float v = fmaxf(hm, 0.f) * w_m2[t];
#pragma unroll
        for (int offd = 32; offd > 0; offd >>= 1) v += __shfl_down(v, offd);
        if (t == 0) out[b] = v + b_m2[0];
    }
}

extern "C" void kernel_launch(void* const* d_in, const int* in_sizes, int n_in,
                              void* d_out, int out_size, void* d_ws, size_t ws_size,
                              hipStream_t stream) {
    const float* x = (const float*)d_in[0];
    const int* ei = (const int*)d_in[1];
    const int* batch = (const int*)d_in[2];
    const float* w_in = (const float*)d_in[3];
    const float* b_in = (const float*)d_in[4];
    const float* w[3] = {(const float*)d_in[5], (const float*)d_in[9], (const float*)d_in[13]};
    const float* asrc[3] = {(const float*)d_in[6], (const float*)d_in[10], (const float*)d_in[14]};
    const float* adst[3] = {(const float*)d_in[7], (const float*)d_in[11], (const float*)d_in[15]};
    const float* bb[3] = {(const float*)d_in[8], (const float*)d_in[12], (const float*)d_in[16]};
    const float* w_fp = (const float*)d_in[17];
    const float* b_fp = (const float*)d_in[18];
    const float* w_m1 = (const float*)d_in[19];
    const float* b_m1 = (const float*)d_in[20];
    const float* w_m2 = (const float*)d_in[21];
    const float* b_m2 = (const float*)d_in[22];

    int n = in_sizes[0] / 128;
    int e = in_sizes[1] / 2;
    int B = out_size;

    char* wsb = (char*)d_ws;
    size_t off = 0;
    auto alloc = [&](size_t bytes) -> void* {
        void* p = wsb + off;
        off += (bytes + 255) & ~(size_t)255;
        return p;
    };
    ushort* hAu = (ushort*)alloc((size_t)n * 128 * 2);  // agg concat out (bf16)
    ushort* hBu = (ushort*)alloc((size_t)n * 128 * 2);  // per-layer gemm out (bf16)
    float* h3 = (float*)alloc((size_t)n * 32 * 4);      // layer-3 agg out (fp32)
    float* als = (float*)alloc((size_t)n * 4 * 4);
    float* ald = (float*)alloc((size_t)n * 4 * 4);
    int* deg = (int*)alloc((size_t)n * 4);              // reused as cursor
    int* rowp = (int*)alloc((size_t)(n + 1) * 4);
    int* col = (int*)alloc((size_t)(e + 8) * 4);
    int* bsums = (int*)alloc(4096);
    ushort* whi = (ushort*)alloc((size_t)3 * 16384 * 2);
    ushort* wlo = (ushort*)alloc((size_t)3 * 16384 * 2);
    float* beff = (float*)alloc(128 * 4);

    const int* srcp = ei;
    const int* dstp = ei + e;
    const float* w0p = w[0];
    const float* w1p = w[1];
    const float* w2p = w[2];

    // single cooperative dispatch: weight pack + deg zero + hist + scan + fill
    {
        void* params[] = {(void*)&srcp, (void*)&dstp, (void*)&e, (void*)&n,
                          (void*)&w_in, (void*)&w0p, (void*)&w1p, (void*)&w2p, (void*)&b_in,
                          (void*)&whi, (void*)&wlo, (void*)&beff,
                          (void*)&deg, (void*)&rowp, (void*)&col, (void*)&bsums};
        hipLaunchCooperativeKernel((const void*)coopbuild_kernel, dim3(1024), dim3(256),
                                   params, 0, stream);
    }

    int ntiles = (n + 31) / 32;
    int gblk = ntiles < 512 ? ntiles : 512;
    int gridAgg = (n + 7) / 8; // 2 nodes/wave, 4 waves/block

    // layer 0: folded gemm x @ (w_in@w0) + b_in@w0 (fp32 A split hi/lo), fused AL
    gemm_mfma_kernel<true, true, false><<<gblk, 512, 0, stream>>>(
        x, whi, wlo, beff, hBu, n, ntiles, asrc[0], adst[0], als, ald);
    agg_kernel<true><<<gridAgg, 256, 0, stream>>>(hBu, als, ald, rowp, col, bb[0],
                                                  hAu, nullptr, n);

    // layers 1,2: gemm hAu->hBu (bf16 A, +fused AL), fused-exp aggregate
    for (int L = 1; L < 3; ++L) {
        gemm_mfma_kernel<false, true, true><<<gblk, 512, 0, stream>>>(
            hAu, whi + (size_t)L * 16384, wlo + (size_t)L * 16384, nullptr, hBu, n,
            ntiles, asrc[L], adst[L], als, ald);
        if (L < 2)
            agg_kernel<true><<<gridAgg, 256, 0, stream>>>(hBu, als, ald, rowp, col, bb[L],
                                                          hAu, nullptr, n);
        else
            agg_kernel<false><<<gridAgg, 256, 0, stream>>>(hBu, als, ald, rowp, col, bb[L],
                                                           nullptr, h3, n);
    }

    // fused pooling + MLP head
    poolmlp_kernel<<<B, 256, 0, stream>>>(h3, batch, n, w_fp, b_fp, w_m1, b_m1, w_m2, b_m2,
                                          (float*)d_out);
}

// Round 15
// 282.599 us; speedup vs baseline: 3.2961x; 3.2961x over previous
//
#include <hip/hip_runtime.h>

#define NEG 0.2f

typedef short s16x8 __attribute__((ext_vector_type(8)));
typedef float f32x4 __attribute__((ext_vector_type(4)));

__device__ __forceinline__ float lrelu(float x) { return x >= 0.f ? x : NEG * x; }
__device__ __forceinline__ float elu1(float x) { return x > 0.f ? x : __expf(x) - 1.f; }

__device__ __forceinline__ unsigned bf16rn(float f) {
    unsigned u = __float_as_uint(f);
    u += 0x7fffu + ((u >> 16) & 1u);
    return u >> 16;
}
__device__ __forceinline__ float bf16tof(ushort h) {
    return __uint_as_float(((unsigned)h) << 16);
}
__device__ __forceinline__ float bf16lo(unsigned u) { return __uint_as_float(u << 16); }
__device__ __forceinline__ float bf16hi(unsigned u) { return __uint_as_float(u & 0xffff0000u); }

// ----------------- XCD-partitioned dst-CSR build -----------------
__global__ void hist_kernel(const int* __restrict__ dst, int e, int n, int* __restrict__ deg) {
    int p = blockIdx.x & 7;
    int s = blockIdx.x >> 3;
    int nslices = gridDim.x >> 3;
    int rng = (n + 7) >> 3;
    int lo = p * rng, hi = min(n, lo + rng);
    int chunk = (e + nslices - 1) / nslices;
    int i0 = s * chunk, i1 = min(e, i0 + chunk);
    for (int i = i0 + threadIdx.x; i < i1; i += blockDim.x) {
        int d = dst[i];
        if (d >= lo && d < hi) atomicAdd(&deg[d], 1);
    }
}

__device__ __forceinline__ int waveIncScanI(int v, int lane) {
#pragma unroll
    for (int off = 1; off < 64; off <<= 1) {
        int u = __shfl_up(v, off);
        if (lane >= off) v += u;
    }
    return v;
}

__global__ void scan1_kernel(const int* __restrict__ deg, int nk,
                             int* __restrict__ rowp, int* __restrict__ bsums) {
    int t = threadIdx.x;
    int base = blockIdx.x * 2048 + t * 8;
    int vals[8];
    int sum = 0;
#pragma unroll
    for (int i = 0; i < 8; ++i) {
        int idx = base + i;
        int v = (idx < nk) ? deg[idx] : 0;
        vals[i] = sum;
        sum += v;
    }
    int lane = t & 63, w = t >> 6;
    int inc = waveIncScanI(sum, lane);
    __shared__ int wsums[4];
    if (lane == 63) wsums[w] = inc;
    __syncthreads();
    int wpre = 0;
#pragma unroll
    for (int i = 0; i < 3; ++i) wpre += (i < w) ? wsums[i] : 0;
    int exc = wpre + inc - sum;
#pragma unroll
    for (int i = 0; i < 8; ++i) {
        int idx = base + i;
        if (idx < nk) rowp[idx] = exc + vals[i];
    }
    if (t == 255) bsums[blockIdx.x] = wpre + inc;
}

// scan3: per-block prefix computed locally from bsums (merged scan2), copy cursor
__global__ void scan3_kernel(int* __restrict__ rowp, const int* __restrict__ bsums,
                             int nk, int total, int* __restrict__ cursor) {
    int g = blockIdx.x;
    __shared__ int spre;
    if (threadIdx.x < 64) {
        int lane = threadIdx.x;
        int v = 0;
        for (int base = lane; base < g; base += 64) v += bsums[base];
#pragma unroll
        for (int off = 32; off > 0; off >>= 1) v += __shfl_xor(v, off);
        if (lane == 0) spre = v;
    }
    __syncthreads();
    int pre = spre;
    int base = g * 2048 + threadIdx.x * 8;
#pragma unroll
    for (int i = 0; i < 8; ++i) {
        int idx = base + i;
        if (idx < nk) {
            int v = rowp[idx] + pre;
            rowp[idx] = v;
            cursor[idx] = v;
        } else if (idx == nk) {
            rowp[nk] = total;
        }
    }
}

__global__ void fill_kernel(const int* __restrict__ src, const int* __restrict__ dst, int e,
                            int n, int* __restrict__ cursor, int* __restrict__ col) {
    int p = blockIdx.x & 7;
    int s = blockIdx.x >> 3;
    int nslices = gridDim.x >> 3;
    int rng = (n + 7) >> 3;
    int lo = p * rng, hi = min(n, lo + rng);
    int chunk = (e + nslices - 1) / nslices;
    int i0 = s * chunk, i1 = min(e, i0 + chunk);
    for (int i = i0 + threadIdx.x; i < i1; i += blockDim.x) {
        int d = dst[i];
        if (d >= lo && d < hi) {
            int pos = atomicAdd(&cursor[d], 1);
            col[pos] = src[i];
        }
    }
}

// ----------------- W pre-pack (3 layers): layer 0 = w_in@w0 (folded proj), layers 1,2 direct.
// Also emits b_eff = b_in@w0, and zeroes deg (replaces memset dispatch).
__global__ void wpack_kernel(const float* __restrict__ w_in, const float* __restrict__ w0,
                             const float* __restrict__ w1, const float* __restrict__ w2,
                             const float* __restrict__ b_in,
                             ushort* __restrict__ whi, ushort* __restrict__ wlo,
                             float* __restrict__ beff, int n, int* __restrict__ degz) {
    int idx = blockIdx.x * 256 + threadIdx.x; // 3*16384 work items
    int stride = gridDim.x * 256;
    for (int i = idx; i < n; i += stride) degz[i] = 0;
    if (idx >= 3 * 16384) return;
    int layer = idx >> 14, e = idx & 16383;
    int k = e >> 7, c = e & 127;
    float wv;
    if (layer == 0) {
        float s = 0.f;
        for (int m = 0; m < 128; ++m) s += w_in[k * 128 + m] * w0[m * 128 + c];
        wv = s;
    } else {
        const float* W = (layer == 1) ? w1 : w2;
        wv = W[e];
    }
    ushort hi = (ushort)bf16rn(wv);
    ushort lo = (ushort)bf16rn(wv - bf16tof(hi));
    int kt = k >> 5, kk = k & 31, j = kk & 7;
    int ln = ((kk >> 3) << 4) | (c & 15);
    int ntg = c >> 4;
    int pos = (layer << 14) + (((kt << 3) + ntg) * 64 + ln) * 8 + j;
    whi[pos] = hi;
    wlo[pos] = lo;
    if (idx < 128) {
        float s = 0.f;
        for (int m = 0; m < 128; ++m) s += b_in[m] * w0[m * 128 + idx];
        beff[idx] = s;
    }
}

// ----------------- MFMA split-bf16 GEMM, double-buffered LDS staging (1 barrier/tile)
// out[n,128](bf16) = A[n,128] @ W[128,128] (+bias); fused attention logits from biased out.
template <bool BIAS, bool AL, bool ABF16>
__global__ __launch_bounds__(512, 2) void gemm_mfma_kernel(
    const void* __restrict__ Av, const ushort* __restrict__ whi, const ushort* __restrict__ wlo,
    const float* __restrict__ bias, ushort* __restrict__ outb, int n, int ntiles,
    const float* __restrict__ asrc, const float* __restrict__ adst,
    float* __restrict__ als, float* __restrict__ ald) {
    __shared__ s16x8 ahi[2][2][4][64]; // [dbuf][mhalf][kt][lane]
    __shared__ s16x8 alo[2][2][4][64];
    int t = threadIdx.x;
    int wid = t >> 6, lane = t & 63;
    int ntp = wid & 3;    // head / 32-col pair
    int mhalf = wid >> 2; // which 16-row half

    const s16x8* wph = (const s16x8*)whi;
    const s16x8* wpl = (const s16x8*)wlo;
    s16x8 wh[4][2], wl[4][2];
#pragma unroll
    for (int kt = 0; kt < 4; ++kt)
#pragma unroll
        for (int j = 0; j < 2; ++j) {
            int ntg = ntp * 2 + j;
            wh[kt][j] = wph[((kt << 3) + ntg) * 64 + lane];
            wl[kt][j] = wpl[((kt << 3) + ntg) * 64 + lane];
        }

    int c0 = ntp * 32 + (lane & 15);
    int c1 = c0 + 16;
    float bv0 = 0.f, bv1 = 0.f;
    if (BIAS) { bv0 = bias[c0]; bv1 = bias[c1]; }
    float as0 = 0.f, as1 = 0.f, ad0 = 0.f, ad1 = 0.f;
    if (AL) {
        as0 = asrc[ntp * 32 + (lane & 15)];
        as1 = asrc[ntp * 32 + 16 + (lane & 15)];
        ad0 = adst[ntp * 32 + (lane & 15)];
        ad1 = adst[ntp * 32 + 16 + (lane & 15)];
    }

    int srow = t >> 4, skoct = t & 15;
    int smh = srow >> 4, skt = skoct >> 2;
    int sln = ((skoct & 3) << 4) | (srow & 15);

    auto stage = [&](int tile, int bi) {
        int gr = tile * 32 + srow;
        if (ABF16) {
            const ushort* Ab = (const ushort*)Av;
            s16x8 hi = {0, 0, 0, 0, 0, 0, 0, 0};
            if (gr < n) hi = *(const s16x8*)(Ab + (size_t)gr * 128 + skoct * 8);
            ahi[bi][smh][skt][sln] = hi;
        } else {
            const float* Af = (const float*)Av;
            float4 v0 = make_float4(0.f, 0.f, 0.f, 0.f), v1 = v0;
            if (gr < n) {
                const float4* rp = (const float4*)(Af + (size_t)gr * 128 + skoct * 8);
                v0 = rp[0];
                v1 = rp[1];
            }
            float f[8] = {v0.x, v0.y, v0.z, v0.w, v1.x, v1.y, v1.z, v1.w};
            s16x8 hi, lo;
#pragma unroll
            for (int j = 0; j < 8; ++j) {
                ushort h = (ushort)bf16rn(f[j]);
                hi[j] = (short)h;
                lo[j] = (short)bf16rn(f[j] - bf16tof(h));
            }
            ahi[bi][smh][skt][sln] = hi;
            alo[bi][smh][skt][sln] = lo;
        }
    };

    int tile = blockIdx.x;
    if (tile < ntiles) stage(tile, 0);
    int cur = 0;
    __syncthreads();

    for (; tile < ntiles; tile += gridDim.x) {
        int nxt = tile + gridDim.x;
        if (nxt < ntiles) stage(nxt, cur ^ 1);

        f32x4 acc0 = {0.f, 0.f, 0.f, 0.f};
        f32x4 acc1 = {0.f, 0.f, 0.f, 0.f};
#pragma unroll
        for (int kt = 0; kt < 4; ++kt) {
            s16x8 ah = ahi[cur][mhalf][kt][lane];
            if (ABF16) {
                acc0 = __builtin_amdgcn_mfma_f32_16x16x32_bf16(ah, wh[kt][0], acc0, 0, 0, 0);
                acc0 = __builtin_amdgcn_mfma_f32_16x16x32_bf16(ah, wl[kt][0], acc0, 0, 0, 0);
                acc1 = __builtin_amdgcn_mfma_f32_16x16x32_bf16(ah, wh[kt][1], acc1, 0, 0, 0);
                acc1 = __builtin_amdgcn_mfma_f32_16x16x32_bf16(ah, wl[kt][1], acc1, 0, 0, 0);
            } else {
                s16x8 al = alo[cur][mhalf][kt][lane];
                acc0 = __builtin_amdgcn_mfma_f32_16x16x32_bf16(ah, wh[kt][0], acc0, 0, 0, 0);
                acc0 = __builtin_amdgcn_mfma_f32_16x16x32_bf16(ah, wl[kt][0], acc0, 0, 0, 0);
                acc0 = __builtin_amdgcn_mfma_f32_16x16x32_bf16(al, wh[kt][0], acc0, 0, 0, 0);
                acc1 = __builtin_amdgcn_mfma_f32_16x16x32_bf16(ah, wh[kt][1], acc1, 0, 0, 0);
                acc1 = __builtin_amdgcn_mfma_f32_16x16x32_bf16(ah, wl[kt][1], acc1, 0, 0, 0);
                acc1 = __builtin_amdgcn_mfma_f32_16x16x32_bf16(al, wh[kt][1], acc1, 0, 0, 0);
            }
        }

        int rbase = tile * 32 + mhalf * 16 + (lane >> 4) * 4;
#pragma unroll
        for (int i = 0; i < 4; ++i) {
            int r = rbase + i;
            float o0 = acc0[i] + bv0;
            float o1 = acc1[i] + bv1;
            if (r < n) {
                outb[(size_t)r * 128 + c0] = (ushort)bf16rn(o0);
                outb[(size_t)r * 128 + c1] = (ushort)bf16rn(o1);
            }
            if (AL) {
                float ps = o0 * as0 + o1 * as1;
                float pd = o0 * ad0 + o1 * ad1;
                ps += __shfl_xor(ps, 1); ps += __shfl_xor(ps, 2);
                ps += __shfl_xor(ps, 4); ps += __shfl_xor(ps, 8);
                pd += __shfl_xor(pd, 1); pd += __shfl_xor(pd, 2);
                pd += __shfl_xor(pd, 4); pd += __shfl_xor(pd, 8);
                if ((lane & 15) == 0 && r < n) {
                    als[r * 4 + ntp] = ps;
                    ald[r * 4 + ntp] = pd;
                }
            }
        }
        __syncthreads();
        cur ^= 1;
    }
}

// ----------------- GAT aggregation: TWO nodes per wave (32 lanes / 4 channels each);
// exp(lrelu(..)) by lane specialization + shfl; bf16 rows; inline self-loop. -----------------
template <bool CONCAT>
__global__ void agg_kernel(const ushort* __restrict__ hp, const float* __restrict__ als,
                           const float* __restrict__ ald_, const int* __restrict__ rowp,
                           const int* __restrict__ col, const float* __restrict__ bias,
                           ushort* __restrict__ outb, float* __restrict__ outf, int n) {
    int lane = threadIdx.x & 63;
    int hl = lane & 31;   // lane within half-wave
    int wid = (blockIdx.x * blockDim.x + threadIdx.x) >> 6;
    int d = wid * 2 + (lane >> 5);
    bool valid = d < n;
    int dc = valid ? d : (n - 1);

    int h = hl >> 3;      // data head (this lane's 4 channels)
    int c4 = hl * 4;      // channel base 0..124
    int hh = hl & 3;      // exp-duty head
    int jl = hl >> 2;     // exp-duty edge slot 0..7
    int bshf = lane & 32; // half base for shuffles

    int start = rowp[dc];
    int end = valid ? rowp[dc + 1] : start;

    float aldv_hh = ald_[dc * 4 + hh];
    float eself = __expf(lrelu(als[dc * 4 + h] + ald_[dc * 4 + h]));

    uint2 sv = *(const uint2*)(hp + (size_t)dc * 128 + c4);
    float a0 = eself * bf16lo(sv.x), a1 = eself * bf16hi(sv.x);
    float a2 = eself * bf16lo(sv.y), a3 = eself * bf16hi(sv.y);
    float esum = eself;

    int iters = (end - start + 7) >> 3;
    int oiters = __shfl_xor(iters, 32);
    int maxit = iters > oiters ? iters : oiters;
    unsigned nclamp = (unsigned)(n - 1);

    for (int it = 0; it < maxit; ++it) {
        int p0 = start + it * 8;
        bool act = p0 < end;
        int pc = act ? p0 : start;
        int4 ca = *(const int4*)(col + pc);
        int4 cb = *(const int4*)(col + pc + 4);
        int v0 = (jl & 4) ? cb.x : ca.x;
        int v1 = (jl & 4) ? cb.y : ca.y;
        int v2 = (jl & 4) ? cb.z : ca.z;
        int v3 = (jl & 4) ? cb.w : ca.w;
        int w0_ = (jl & 2) ? v2 : v0;
        int w1_ = (jl & 2) ? v3 : v1;
        unsigned se = (unsigned)((jl & 1) ? w1_ : w0_);
        se = se > nclamp ? nclamp : se;
        float ee = __expf(lrelu(als[(size_t)se * 4 + hh] + aldv_hh));
        ee = (act && (p0 + jl < end)) ? ee : 0.f;

#define EDGE(JJ, SRC)                                                              \
        {                                                                          \
            float ej = __shfl(ee, bshf | (JJ << 2) | h);                           \
            unsigned sju = (unsigned)(SRC);                                        \
            sju = sju > nclamp ? nclamp : sju;                                     \
            uint2 uv = *(const uint2*)(hp + (size_t)sju * 128 + c4);               \
            a0 += ej * bf16lo(uv.x); a1 += ej * bf16hi(uv.x);                      \
            a2 += ej * bf16lo(uv.y); a3 += ej * bf16hi(uv.y);                      \
            esum += ej;                                                            \
        }
        EDGE(0, ca.x) EDGE(1, ca.y) EDGE(2, ca.z) EDGE(3, ca.w)
        EDGE(4, cb.x) EDGE(5, cb.y) EDGE(6, cb.z) EDGE(7, cb.w)
#undef EDGE
    }

    float inv = 1.f / (esum + 1e-16f);
    a0 *= inv; a1 *= inv; a2 *= inv; a3 *= inv;
    if (CONCAT) {
        if (valid) {
            float o0 = elu1(a0 + bias[c4]);
            float o1 = elu1(a1 + bias[c4 + 1]);
            float o2 = elu1(a2 + bias[c4 + 2]);
            float o3 = elu1(a3 + bias[c4 + 3]);
            uint2 pk;
            pk.x = bf16rn(o0) | (bf16rn(o1) << 16);
            pk.y = bf16rn(o2) | (bf16rn(o3) << 16);
            *(uint2*)(outb + (size_t)d * 128 + c4) = pk;
        }
    } else {
        a0 += __shfl_xor(a0, 8); a0 += __shfl_xor(a0, 16);
        a1 += __shfl_xor(a1, 8); a1 += __shfl_xor(a1, 16);
        a2 += __shfl_xor(a2, 8); a2 += __shfl_xor(a2, 16);
        a3 += __shfl_xor(a3, 8); a3 += __shfl_xor(a3, 16);
        if (valid && hl < 8) {
            int cin = hl * 4;
            float4 o;
            o.x = elu1(a0 * 0.25f + bias[cin]);
            o.y = elu1(a1 * 0.25f + bias[cin + 1]);
            o.z = elu1(a2 * 0.25f + bias[cin + 2]);
            o.w = elu1(a3 * 0.25f + bias[cin + 3]);
            *(float4*)(outf + (size_t)d * 32 + cin) = o;
        }
    }
}

// ----------------- fused mean-pool + final_proj + MLP head, one block per batch row ---------
__global__ void poolmlp_kernel(const float* __restrict__ h2, const int* __restrict__ batch,
                               int n, const float* __restrict__ w_fp,
                               const float* __restrict__ b_fp, const float* __restrict__ w_m1,
                               const float* __restrict__ b_m1, const float* __restrict__ w_m2,
                               const float* __restrict__ b_m2, float* __restrict__ out) {
    int b = blockIdx.x, t = threadIdx.x; // 256 threads
    __shared__ int sb[2];
    if (t == 0) {
        int lo = 0, hi = n;
        while (lo < hi) { int mid = (lo + hi) >> 1; if (batch[mid] < b) lo = mid + 1; else hi = mid; }
        sb[0] = lo;
        int lo2 = lo, hi2 = n;
        while (lo2 < hi2) { int mid = (lo2 + hi2) >> 1; if (batch[mid] < b + 1) lo2 = mid + 1; else hi2 = mid; }
        sb[1] = lo2;
    }
    __syncthreads();
    int lo = sb[0], hi = sb[1];
    int c = t & 31, g = t >> 5; // 8 groups of 32
    float acc = 0.f;
    for (int i = lo + g; i < hi; i += 8) acc += h2[(size_t)i * 32 + c];
    __shared__ float red[8][32];
    __shared__ float sp[32], so[128];
    red[g][c] = acc;
    __syncthreads();
    if (t < 32) {
        float s = 0.f;
#pragma unroll
        for (int g2 = 0; g2 < 8; ++g2) s += red[g2][t];
        float cnt = (float)(hi - lo);
        sp[t] = s / fmaxf(cnt, 1.f);
    }
    __syncthreads();
    if (t < 128) {
        float o = b_fp[t];
#pragma unroll 8
        for (int k = 0; k < 32; ++k) o += sp[k] * w_fp[k * 128 + t];
        so[t] = o;
    }
    __syncthreads();
    if (t < 64) {
        float hm = b_m1[t];
        for (int cc = 0; cc < 128; ++cc) hm += so[cc] * w_m1[cc * 64 + t];
        float v = fmaxf(hm, 0.f) * w_m2[t];
#pragma unroll
        for (int offd = 32; offd > 0; offd >>= 1) v += __shfl_down(v, offd);
        if (t == 0) out[b] = v + b_m2[0];
    }
}

extern "C" void kernel_launch(void* const* d_in, const int* in_sizes, int n_in,
                              void* d_out, int out_size, void* d_ws, size_t ws_size,
                              hipStream_t stream) {
    const float* x = (const float*)d_in[0];
    const int* ei = (const int*)d_in[1];
    const int* batch = (const int*)d_in[2];
    const float* w_in = (const float*)d_in[3];
    const float* b_in = (const float*)d_in[4];
    const float* w[3] = {(const float*)d_in[5], (const float*)d_in[9], (const float*)d_in[13]};
    const float* asrc[3] = {(const float*)d_in[6], (const float*)d_in[10], (const float*)d_in[14]};
    const float* adst[3] = {(const float*)d_in[7], (const float*)d_in[11], (const float*)d_in[15]};
    const float* bb[3] = {(const float*)d_in[8], (const float*)d_in[12], (const float*)d_in[16]};
    const float* w_fp = (const float*)d_in[17];
    const float* b_fp = (const float*)d_in[18];
    const float* w_m1 = (const float*)d_in[19];
    const float* b_m1 = (const float*)d_in[20];
    const float* w_m2 = (const float*)d_in[21];
    const float* b_m2 = (const float*)d_in[22];

    int n = in_sizes[0] / 128;
    int e = in_sizes[1] / 2;
    int B = out_size;

    char* wsb = (char*)d_ws;
    size_t off = 0;
    auto alloc = [&](size_t bytes) -> void* {
        void* p = wsb + off;
        off += (bytes + 255) & ~(size_t)255;
        return p;
    };
    ushort* hAu = (ushort*)alloc((size_t)n * 128 * 2);  // agg concat out (bf16)
    ushort* hBu = (ushort*)alloc((size_t)n * 128 * 2);  // per-layer gemm out (bf16)
    float* h3 = (float*)alloc((size_t)n * 32 * 4);      // layer-3 agg out (fp32)
    float* als = (float*)alloc((size_t)n * 4 * 4);
    float* ald = (float*)alloc((size_t)n * 4 * 4);
    int* deg = (int*)alloc((size_t)n * 4);              // reused as cursor
    int* rowp = (int*)alloc((size_t)(n + 1) * 4);
    int* col = (int*)alloc((size_t)(e + 8) * 4);
    int* bsums = (int*)alloc(4096);
    ushort* whi = (ushort*)alloc((size_t)3 * 16384 * 2);
    ushort* wlo = (ushort*)alloc((size_t)3 * 16384 * 2);
    float* beff = (float*)alloc(128 * 4);

    const int* srcp = ei;
    const int* dstp = ei + e;

    // weights pack + zero deg (1 dispatch, replaces memset)
    wpack_kernel<<<192, 256, 0, stream>>>(w_in, w[0], w[1], w[2], b_in, whi, wlo, beff,
                                          n, deg);

    // XCD-partitioned dst-CSR — graph shared by all 3 layers
    hist_kernel<<<1024, 256, 0, stream>>>(dstp, e, n, deg);
    int nb = (n + 2047) / 2048;
    scan1_kernel<<<nb, 256, 0, stream>>>(deg, n, rowp, bsums);
    scan3_kernel<<<nb, 256, 0, stream>>>(rowp, bsums, n, e, deg);
    fill_kernel<<<1024, 256, 0, stream>>>(srcp, dstp, e, n, deg, col);

    int ntiles = (n + 31) / 32;
    int gblk = ntiles < 512 ? ntiles : 512;
    int gridAgg = (n + 7) / 8; // 2 nodes/wave, 4 waves/block

    // layer 0: folded gemm x @ (w_in@w0) + b_in@w0 (fp32 A split hi/lo), fused AL
    gemm_mfma_kernel<true, true, false><<<gblk, 512, 0, stream>>>(
        x, whi, wlo, beff, hBu, n, ntiles, asrc[0], adst[0], als, ald);
    agg_kernel<true><<<gridAgg, 256, 0, stream>>>(hBu, als, ald, rowp, col, bb[0],
                                                  hAu, nullptr, n);

    // layers 1,2: gemm hAu->hBu (bf16 A, +fused AL), fused-exp aggregate
    for (int L = 1; L < 3; ++L) {
        gemm_mfma_kernel<false, true, true><<<gblk, 512, 0, stream>>>(
            hAu, whi + (size_t)L * 16384, wlo + (size_t)L * 16384, nullptr, hBu, n,
            ntiles, asrc[L], adst[L], als, ald);
        if (L < 2)
            agg_kernel<true><<<gridAgg, 256, 0, stream>>>(hBu, als, ald, rowp, col, bb[L],
                                                          hAu, nullptr, n);
        else
            agg_kernel<false><<<gridAgg, 256, 0, stream>>>(hBu, als, ald, rowp, col, bb[L],
                                                           nullptr, h3, n);
    }

    // fused pooling + MLP head
    poolmlp_kernel<<<B, 256, 0, stream>>>(h3, batch, n, w_fp, b_fp, w_m1, b_m1, w_m2, b_m2,
                                          (float*)d_out);
}